// Round 6
// baseline (239.290 us; speedup 1.0000x reference)
//
#include <hip/hip_runtime.h>

#define DD 128          // embedding dim
#define KK 64           // neighbors
#define NT 256          // threads per block = 4 waves
#define WPB 4           // units (waves) per block
#define NCHUNK 4
#define LPC 8           // load instructions per chunk; each covers rows (j, j+32)

__global__ __launch_bounds__(NT, 8) void ga_kernel(
    const int*   __restrict__ node_ids,      // [B3]
    const int*   __restrict__ neighbor_ids,  // [B3*K]
    const int*   __restrict__ neighbor_mask, // [B3*K]
    const float* __restrict__ emb,           // [V*D]
    const float* __restrict__ gamma,
    const float* __restrict__ beta,
    float*       __restrict__ out,           // [B3*D]
    int B3)
{
    const int t = threadIdx.x;
    const int l = t & 63;                 // lane in wave
    const int w = t >> 6;                 // wave in block
    const int unit = blockIdx.x * WPB + w;
    if (unit >= B3) return;

    const int c = l & 31;                 // float4 column chunk (cols 4c..4c+3)

    // per-lane neighbor id; mask condensed to one wave-uniform ballot word
    const int kb   = unit * KK;
    const int myid = neighbor_ids[kb + l];
    const int mym  = neighbor_mask[kb + l];
    const unsigned long long mbits = __ballot(mym != 0);
    // lanes 0-31 test bits 0..31 (rows 0..31); lanes 32-63 test bits 32..63
    const unsigned int word = (l & 32) ? (unsigned int)(mbits >> 32)
                                       : (unsigned int)mbits;

    // node row: lanes c and c+32 load the same float4 (one 512B coalesced fetch)
    const long long nodeid = (long long)node_ids[unit];
    const float4 nv = ((const float4*)(emb + (size_t)nodeid * DD))[c];

    float4 acc = make_float4(0.f, 0.f, 0.f, 0.f);

    for (int cc = 0; cc < NCHUNK; ++cc) {
        // distribute ids: instr j -> lower half gets id[base+j], upper id[base+j+32]
        int ids[LPC];
        #pragma unroll
        for (int j = 0; j < LPC; ++j) {
            ids[j] = __shfl(myid, cc * LPC + j, 32);
        }
        // issue 8 pair-loads (1 KB each, exec-masked by neighbor mask)
        float4 v[LPC];
        #pragma unroll
        for (int j = 0; j < LPC; ++j) {
            const int jj = cc * LPC + j;
            v[j] = make_float4(0.f, 0.f, 0.f, 0.f);
            if ((word >> jj) & 1u) {
                v[j] = ((const float4*)(emb + (size_t)(unsigned)ids[j] * DD))[c];
            }
        }
        // 8 independent dot/reduce/accumulate chains (reduce within 32-lane half)
        #pragma unroll
        for (int j = 0; j < LPC; ++j) {
            float p = v[j].x * nv.x + v[j].y * nv.y + v[j].z * nv.z + v[j].w * nv.w;
            p += __shfl_xor(p, 16);
            p += __shfl_xor(p, 8);
            p += __shfl_xor(p, 4);
            p += __shfl_xor(p, 2);
            p += __shfl_xor(p, 1);
            const float att = p * (1.0f / 15.0f);
            acc.x += att * v[j].x;
            acc.y += att * v[j].y;
            acc.z += att * v[j].z;
            acc.w += att * v[j].w;
        }
    }

    // combine halves: lower half holds rows 0-31 contribution, upper rows 32-63
    acc.x += __shfl_xor(acc.x, 32);
    acc.y += __shfl_xor(acc.y, 32);
    acc.z += __shfl_xor(acc.z, 32);
    acc.w += __shfl_xor(acc.w, 32);

    // x = node + att_out (all lanes hold cols 4c..4c+3; halves duplicate)
    float4 x;
    x.x = nv.x + acc.x;
    x.y = nv.y + acc.y;
    x.z = nv.z + acc.z;
    x.w = nv.w + acc.w;

    // layernorm stats: sum over one 32-lane half covers all 128 values
    float s = x.x + x.y + x.z + x.w;
    s += __shfl_xor(s, 16); s += __shfl_xor(s, 8); s += __shfl_xor(s, 4);
    s += __shfl_xor(s, 2);  s += __shfl_xor(s, 1);
    const float mu = s * (1.0f / 128.0f);
    const float dx = x.x - mu, dy = x.y - mu, dz = x.z - mu, dw = x.w - mu;
    float v2 = dx * dx + dy * dy + dz * dz + dw * dw;
    v2 += __shfl_xor(v2, 16); v2 += __shfl_xor(v2, 8); v2 += __shfl_xor(v2, 4);
    v2 += __shfl_xor(v2, 2);  v2 += __shfl_xor(v2, 1);
    const float rs = rsqrtf(v2 * (1.0f / 128.0f) + 1e-5f);

    // store: lower half writes the 512B output row (coalesced)
    if (l < 32) {
        const float4 gm = ((const float4*)gamma)[c];
        const float4 bt = ((const float4*)beta)[c];
        float4 o;
        o.x = dx * rs * gm.x + bt.x;
        o.y = dy * rs * gm.y + bt.y;
        o.z = dz * rs * gm.z + bt.z;
        o.w = dw * rs * gm.w + bt.w;
        ((float4*)(out + (size_t)unit * DD))[c] = o;
    }
}

extern "C" void kernel_launch(void* const* d_in, const int* in_sizes, int n_in,
                              void* d_out, int out_size, void* d_ws, size_t ws_size,
                              hipStream_t stream) {
    const int*   node_ids      = (const int*)  d_in[0];
    const int*   neighbor_ids  = (const int*)  d_in[1];
    const int*   neighbor_mask = (const int*)  d_in[2];
    const float* emb           = (const float*)d_in[3];
    const float* gamma         = (const float*)d_in[4];
    const float* beta          = (const float*)d_in[5];
    float*       out           = (float*)d_out;

    const int B3 = in_sizes[0];  // B*3 = 12288
    const int nblk = (B3 + WPB - 1) / WPB;

    ga_kernel<<<nblk, NT, 0, stream>>>(node_ids, neighbor_ids, neighbor_mask,
                                       emb, gamma, beta, out, B3);
}

// Round 7
// 52.430 us; speedup vs baseline: 4.5640x; 4.5640x over previous
//
#include <hip/hip_runtime.h>

#define DD 128          // embedding dim
#define KK 64           // neighbors
#define NT 256          // threads per block = 4 waves
#define WPB 4           // units (waves) per block
#define NCHUNK 4
#define LPC 8           // pair-loads per chunk; pair-load jj covers rows (jj, jj+32)

__global__ __launch_bounds__(NT) void ga_kernel(
    const int*   __restrict__ node_ids,      // [B3]
    const int*   __restrict__ neighbor_ids,  // [B3*K]
    const int*   __restrict__ neighbor_mask, // [B3*K]
    const float* __restrict__ emb,           // [V*D]
    const float* __restrict__ gamma,
    const float* __restrict__ beta,
    float*       __restrict__ out,           // [B3*D]
    int B3)
{
    const int t = threadIdx.x;
    const int l = t & 63;                                   // lane in wave
    const int w = __builtin_amdgcn_readfirstlane(t >> 6);   // wave id (SGPR)
    const int unit = blockIdx.x * WPB + w;
    if (unit >= B3) return;

    const int c = l & 31;                 // float4 column chunk (cols 4c..4c+3)
    const int kb = unit * KK;             // wave-uniform -> scalar loads below

    // per-lane mask -> one ballot word; lane's half selects hi/lo 32 bits
    const int mym = neighbor_mask[kb + l];
    const unsigned long long mbits = __ballot(mym != 0);
    const unsigned int word = (l & 32) ? (unsigned int)(mbits >> 32)
                                       : (unsigned int)mbits;

    // node row (both halves read same 512B -> L1 broadcast)
    const int nodeid = node_ids[unit];
    const float4 nv = ((const float4*)(emb + (size_t)(unsigned)nodeid * DD))[c];

    const unsigned coff = (unsigned)c * 16u;
    float4 acc = make_float4(0.f, 0.f, 0.f, 0.f);

    #pragma unroll
    for (int cc = 0; cc < NCHUNK; ++cc) {
        // ---- issue 8 pair-loads (1 KB each: rows jj and jj+32) ----
        float4 v[LPC];
        #pragma unroll
        for (int j = 0; j < LPC; ++j) {
            const int jj = cc * LPC + j;
            // wave-uniform addresses -> scalar (s_load) id fetches, no VGPR array
            const int id_lo = neighbor_ids[kb + jj];
            const int id_hi = neighbor_ids[kb + jj + 32];
            const int id = (l & 32) ? id_hi : id_lo;
            v[j] = make_float4(0.f, 0.f, 0.f, 0.f);
            if ((word >> jj) & 1u) {   // skip load for masked-out rows
                const unsigned off = ((unsigned)id << 9) + coff;  // id*512 + c*16
                v[j] = *(const float4*)((const char*)emb + off);
            }
        }
        // ---- 8 independent dot/reduce/accumulate chains (within 32-lane half) ----
        #pragma unroll
        for (int j = 0; j < LPC; ++j) {
            float p = v[j].x * nv.x + v[j].y * nv.y + v[j].z * nv.z + v[j].w * nv.w;
            p += __shfl_xor(p, 16);
            p += __shfl_xor(p, 8);
            p += __shfl_xor(p, 4);
            p += __shfl_xor(p, 2);
            p += __shfl_xor(p, 1);
            const float att = p * (1.0f / 15.0f);
            acc.x += att * v[j].x;
            acc.y += att * v[j].y;
            acc.z += att * v[j].z;
            acc.w += att * v[j].w;
        }
    }

    // combine halves: lower half has rows 0-31, upper rows 32-63
    acc.x += __shfl_xor(acc.x, 32);
    acc.y += __shfl_xor(acc.y, 32);
    acc.z += __shfl_xor(acc.z, 32);
    acc.w += __shfl_xor(acc.w, 32);

    // x = node + att_out (cols 4c..4c+3, duplicated across halves)
    const float xx = nv.x + acc.x;
    const float xy = nv.y + acc.y;
    const float xz = nv.z + acc.z;
    const float xw = nv.w + acc.w;

    // layernorm stats: reduce within a 32-lane half covers all 128 cols
    float s = xx + xy + xz + xw;
    s += __shfl_xor(s, 16); s += __shfl_xor(s, 8); s += __shfl_xor(s, 4);
    s += __shfl_xor(s, 2);  s += __shfl_xor(s, 1);
    const float mu = s * (1.0f / 128.0f);
    const float dx = xx - mu, dy = xy - mu, dz = xz - mu, dw = xw - mu;
    float v2 = dx * dx + dy * dy + dz * dz + dw * dw;
    v2 += __shfl_xor(v2, 16); v2 += __shfl_xor(v2, 8); v2 += __shfl_xor(v2, 4);
    v2 += __shfl_xor(v2, 2);  v2 += __shfl_xor(v2, 1);
    const float rs = rsqrtf(v2 * (1.0f / 128.0f) + 1e-5f);

    // store: lower half writes the 512B output row (coalesced)
    if (l < 32) {
        const float4 gm = ((const float4*)gamma)[c];
        const float4 bt = ((const float4*)beta)[c];
        float4 o;
        o.x = dx * rs * gm.x + bt.x;
        o.y = dy * rs * gm.y + bt.y;
        o.z = dz * rs * gm.z + bt.z;
        o.w = dw * rs * gm.w + bt.w;
        ((float4*)(out + (size_t)unit * DD))[c] = o;
    }
}

extern "C" void kernel_launch(void* const* d_in, const int* in_sizes, int n_in,
                              void* d_out, int out_size, void* d_ws, size_t ws_size,
                              hipStream_t stream) {
    const int*   node_ids      = (const int*)  d_in[0];
    const int*   neighbor_ids  = (const int*)  d_in[1];
    const int*   neighbor_mask = (const int*)  d_in[2];
    const float* emb           = (const float*)d_in[3];
    const float* gamma         = (const float*)d_in[4];
    const float* beta          = (const float*)d_in[5];
    float*       out           = (float*)d_out;

    const int B3 = in_sizes[0];  // B*3 = 12288
    const int nblk = (B3 + WPB - 1) / WPB;

    ga_kernel<<<nblk, NT, 0, stream>>>(node_ids, neighbor_ids, neighbor_mask,
                                       emb, gamma, beta, out, B3);
}

// Round 8
// 38.482 us; speedup vs baseline: 6.2182x; 1.3624x over previous
//
#include <hip/hip_runtime.h>

#define DD 128          // embedding dim
#define KK 64           // neighbors
#define NT 256          // threads per block = 4 waves = 8 half-wave groups
#define NG 8            // groups of 32 lanes
#define KPG 8           // k's per group

__global__ __launch_bounds__(NT) void ga_kernel(
    const int*   __restrict__ node_ids,      // [B3]
    const int*   __restrict__ neighbor_ids,  // [B3*K]
    const int*   __restrict__ neighbor_mask, // [B3*K]
    const float* __restrict__ emb,           // [V*D]
    const float* __restrict__ gamma,
    const float* __restrict__ beta,
    float*       __restrict__ out,           // [B3*D]
    int B3)
{
    __shared__ float red[NG][DD];   // per-group partial att_out (4 KB)
    __shared__ float node_lds[DD];

    const int blk = blockIdx.x;
    const int t = threadIdx.x;
    const int l = t & 63;          // lane in wave
    const int w = t >> 6;          // wave 0..3
    const int g = t >> 5;          // group 0..7 (half-wave)
    const int c = t & 31;          // float4 column chunk

    // each wave holds all 64 ids/masks in its own lanes (coalesced load,
    // 4x redundant across waves -> L1 hits). No LDS, no barrier.
    const int kb   = blk * KK;
    const int myid = neighbor_ids[kb + l];
    const int mym  = neighbor_mask[kb + l];
    const unsigned long long mbits = __ballot(mym != 0);
    // this group's 8 mask bits: k = g*8 + j -> word (k>>5), bit (k&31)
    const unsigned word  = (w >= 2) ? (unsigned)(mbits >> 32) : (unsigned)mbits;
    const unsigned wordh = word >> ((g & 3) << 3);

    // node row (all groups read same 512B -> L1 broadcast); group 0 stages it
    const int nodeid = node_ids[blk];
    const float4 nv = ((const float4*)(emb + (size_t)(unsigned)nodeid * DD))[c];
    if (t < 32) ((float4*)node_lds)[c] = nv;

    const int base_lane = g << 3;  // k base for this group

    // ---- phase 1: distribute ids in-wave, issue ALL 8 gathers ----
    float4 v[KPG];
    #pragma unroll
    for (int j = 0; j < KPG; ++j) {
        const int id = __shfl(myid, base_lane + j, 64);
        v[j] = make_float4(0.f, 0.f, 0.f, 0.f);
        if ((wordh >> j) & 1u) {   // skip global load for masked-out neighbors
            v[j] = ((const float4*)(emb + (size_t)(unsigned)id * DD))[c];
        }
    }

    // ---- phase 2: 8 independent dot/reduce/accumulate chains ----
    float4 acc = make_float4(0.f, 0.f, 0.f, 0.f);
    #pragma unroll
    for (int j = 0; j < KPG; ++j) {
        float p = v[j].x * nv.x + v[j].y * nv.y + v[j].z * nv.z + v[j].w * nv.w;
        p += __shfl_xor(p, 16);
        p += __shfl_xor(p, 8);
        p += __shfl_xor(p, 4);
        p += __shfl_xor(p, 2);
        p += __shfl_xor(p, 1);
        const float att = p * (1.0f / 15.0f);
        acc.x += att * v[j].x;
        acc.y += att * v[j].y;
        acc.z += att * v[j].z;
        acc.w += att * v[j].w;
    }
    ((float4*)red[g])[c] = acc;
    __syncthreads();

    // ---- fused epilogue: combine partials + layernorm + store (wave 0) ----
    if (t < 64) {
        float x0 = node_lds[t], x1 = node_lds[t + 64];
        #pragma unroll
        for (int gg = 0; gg < NG; ++gg) {
            x0 += red[gg][t];
            x1 += red[gg][t + 64];
        }
        float s = x0 + x1;
        s += __shfl_xor(s, 32); s += __shfl_xor(s, 16); s += __shfl_xor(s, 8);
        s += __shfl_xor(s, 4);  s += __shfl_xor(s, 2);  s += __shfl_xor(s, 1);
        const float mu = s * (1.0f / 128.0f);
        const float d0 = x0 - mu, d1 = x1 - mu;
        float v2 = d0 * d0 + d1 * d1;
        v2 += __shfl_xor(v2, 32); v2 += __shfl_xor(v2, 16); v2 += __shfl_xor(v2, 8);
        v2 += __shfl_xor(v2, 4);  v2 += __shfl_xor(v2, 2);  v2 += __shfl_xor(v2, 1);
        const float rs = rsqrtf(v2 * (1.0f / 128.0f) + 1e-5f);
        const size_t ob = (size_t)blk * DD;
        out[ob + t]      = d0 * rs * gamma[t]      + beta[t];
        out[ob + t + 64] = d1 * rs * gamma[t + 64] + beta[t + 64];
    }
}

extern "C" void kernel_launch(void* const* d_in, const int* in_sizes, int n_in,
                              void* d_out, int out_size, void* d_ws, size_t ws_size,
                              hipStream_t stream) {
    const int*   node_ids      = (const int*)  d_in[0];
    const int*   neighbor_ids  = (const int*)  d_in[1];
    const int*   neighbor_mask = (const int*)  d_in[2];
    const float* emb           = (const float*)d_in[3];
    const float* gamma         = (const float*)d_in[4];
    const float* beta          = (const float*)d_in[5];
    float*       out           = (float*)d_out;

    const int B3 = in_sizes[0];  // B*3 = 12288

    ga_kernel<<<B3, NT, 0, stream>>>(node_ids, neighbor_ids, neighbor_mask,
                                     emb, gamma, beta, out, B3);
}